// Round 15
// baseline (112.182 us; speedup 1.0000x reference)
//
#include <hip/hip_runtime.h>

#define NN 100000
#define NE 1600000

constexpr int F_IN = 58;
constexpr int FH2  = 32;            // KS * F_H
constexpr int KS   = 2;

constexpr int NB   = 782;           // buckets: col >> 7 (99999>>7 = 781)
constexpr int NBLK = 256;           // partition blocks
constexpr int EPB  = NE / NBLK;     // 6250
constexpr int SCANN = NB * NBLK;    // 200192
constexpr int SCAN_BLOCKS = (SCANN + 1023) / 1024;  // 196
constexpr int DN_NODES = 64;
constexpr int DENSE_BLOCKS = (NN + DN_NODES - 1) / DN_NODES;  // 1563
constexpr int LROW = 136;           // padded LDS row stride in shorts

using short8 = __attribute__((ext_vector_type(8))) short;
using f32x4  = __attribute__((ext_vector_type(4))) float;

__device__ inline void splitbf(float v, short& hi, short& lo) {
    unsigned ub = __float_as_uint(v);
    unsigned short h = (unsigned short)(ub >> 16);
    float hif = __uint_as_float(((unsigned)h) << 16);
    float lof = v - hif;
    unsigned short l = (unsigned short)(__float_as_uint(lof) >> 16);
    hi = (short)h; lo = (short)l;
}

// one-time weight split (bf16 hi|lo), layout [c=0..63][k=0..127]
__global__ void k_prep_w(const float* __restrict__ Wi, const float* __restrict__ Wr,
                         short* __restrict__ wpre) {
    int t = threadIdx.x;
    for (int idx = t; idx < 64 * 64; idx += 256) {
        int c = idx >> 6, i = idx & 63;
        int ko = c & 31, kst = ko >> 4, o = ko & 15;
        const float* W = (c < 32) ? Wi : Wr;
        float v = (i < F_IN) ? W[(kst * F_IN + i) * 16 + o] : 0.f;
        short hi, lo; splitbf(v, hi, lo);
        wpre[c * 128 + i] = hi;
        wpre[c * 128 + 64 + i] = lo;
    }
}

// blocks [0,NBLK): per-block bucket histogram (single-copy LDS atomics, int2 loads).
// blocks [NBLK,...): dense layer-1 via split-bf16 MFMA, padded LDS.
__global__ void k_hist_dense1(const int* __restrict__ col, int* __restrict__ bh,
                              const float* __restrict__ x,
                              const short* __restrict__ wpre,
                              const float* __restrict__ b,
                              float* __restrict__ h1, float* __restrict__ r1) {
    __shared__ int hist[NB];
    __shared__ short sA[64 * LROW];
    __shared__ short sB[64 * LROW];
    int tid = threadIdx.x;

    if (blockIdx.x < NBLK) {
        int blk = blockIdx.x;
        for (int i = tid; i < NB; i += 256) hist[i] = 0;
        __syncthreads();
        const int2* c2p = (const int2*)&col[blk * EPB];
        for (int c = tid; c < EPB / 2; c += 256) {
            int2 cc = c2p[c];
            atomicAdd(&hist[cc.x >> 7], 1);
            atomicAdd(&hist[cc.y >> 7], 1);
        }
        __syncthreads();
        for (int i = tid; i < NB; i += 256)
            bh[i * NBLK + blk] = hist[i];
        return;
    }

    int nodeBase = (blockIdx.x - NBLK) * DN_NODES;
    for (int t = tid; t < 1024; t += 256) {
        int c = t >> 4, q8 = t & 15;
        *(short8*)&sB[c * LROW + q8 * 8] = *(const short8*)&wpre[c * 128 + q8 * 8];
    }
    for (int t = tid; t < 1024; t += 256) {
        int r = t >> 4, q4 = t & 15;
        int n = nodeBase + r;
        float v0 = 0.f, v1 = 0.f, v2 = 0.f, v3 = 0.f;
        int i0 = q4 * 4;
        if (n < NN && i0 < F_IN) {
            float2 a = *(const float2*)&x[(size_t)n * F_IN + i0];
            v0 = a.x; v1 = a.y;
            if (i0 + 2 < F_IN) {
                float2 c2 = *(const float2*)&x[(size_t)n * F_IN + i0 + 2];
                v2 = c2.x; v3 = c2.y;
            }
        }
        short h0, l0, h1s, l1s, h2s, l2s, h3s, l3s;
        splitbf(v0, h0, l0); splitbf(v1, h1s, l1s);
        splitbf(v2, h2s, l2s); splitbf(v3, h3s, l3s);
        *(short4*)&sA[r * LROW + q4 * 4]      = make_short4(h0, h1s, h2s, h3s);
        *(short4*)&sA[r * LROW + 64 + q4 * 4] = make_short4(l0, l1s, l2s, l3s);
    }
    __syncthreads();

    int lane = tid & 63, w = tid >> 6;
    int r15 = lane & 15, h4 = lane >> 4;
    const short* aB = &sA[(w * 16 + r15) * LROW];
    f32x4 acc0 = {0,0,0,0}, acc1 = {0,0,0,0}, acc2 = {0,0,0,0}, acc3 = {0,0,0,0};
    const int kaA[6] = {0, 32, 0, 32, 64, 96};
    const int kaB[6] = {0, 32, 64, 96, 0, 32};
#pragma unroll
    for (int s = 0; s < 6; s++) {
        short8 af = *(const short8*)&aB[kaA[s] + h4 * 8];
#define BMM(nt, accv) { \
        short8 bf = *(const short8*)&sB[(nt * 16 + r15) * LROW + kaB[s] + h4 * 8]; \
        accv = __builtin_amdgcn_mfma_f32_16x16x32_bf16(af, bf, accv, 0, 0, 0); }
        BMM(0, acc0) BMM(1, acc1) BMM(2, acc2) BMM(3, acc3)
#undef BMM
    }
    int nb0 = nodeBase + w * 16 + h4 * 4;
#define WH(nt, accv) { int colg = nt * 16 + r15; \
    if (nb0 + 0 < NN) h1[(size_t)(nb0 + 0) * 32 + colg] = accv[0]; \
    if (nb0 + 1 < NN) h1[(size_t)(nb0 + 1) * 32 + colg] = accv[1]; \
    if (nb0 + 2 < NN) h1[(size_t)(nb0 + 2) * 32 + colg] = accv[2]; \
    if (nb0 + 3 < NN) h1[(size_t)(nb0 + 3) * 32 + colg] = accv[3]; }
#define WR(nt, accv) { int colg = nt * 16 + r15 - 32; float bv = b[colg]; \
    if (nb0 + 0 < NN) r1[(size_t)(nb0 + 0) * 32 + colg] = accv[0] + bv; \
    if (nb0 + 1 < NN) r1[(size_t)(nb0 + 1) * 32 + colg] = accv[1] + bv; \
    if (nb0 + 2 < NN) r1[(size_t)(nb0 + 2) * 32 + colg] = accv[2] + bv; \
    if (nb0 + 3 < NN) r1[(size_t)(nb0 + 3) * 32 + colg] = accv[3] + bv; }
    WH(0, acc0) WH(1, acc1) WR(2, acc2) WR(3, acc3)
#undef WH
#undef WR
}

__global__ void k_scan1(int* __restrict__ bh, int* __restrict__ bsum) {
    __shared__ int ts[256];
    int tid = threadIdx.x;
    int base = blockIdx.x * 1024 + tid * 4;
    int v0 = (base + 0 < SCANN) ? bh[base + 0] : 0;
    int v1 = (base + 1 < SCANN) ? bh[base + 1] : 0;
    int v2 = (base + 2 < SCANN) ? bh[base + 2] : 0;
    int v3 = (base + 3 < SCANN) ? bh[base + 3] : 0;
    int p0 = v0, p1 = p0 + v1, p2 = p1 + v2, p3 = p2 + v3;
    ts[tid] = p3;
    __syncthreads();
    for (int off = 1; off < 256; off <<= 1) {
        int v = (tid >= off) ? ts[tid - off] : 0;
        __syncthreads();
        ts[tid] += v;
        __syncthreads();
    }
    int prev = (tid > 0) ? ts[tid - 1] : 0;
    if (base + 0 < SCANN) bh[base + 0] = prev + p0;
    if (base + 1 < SCANN) bh[base + 1] = prev + p1;
    if (base + 2 < SCANN) bh[base + 2] = prev + p2;
    if (base + 3 < SCANN) bh[base + 3] = prev + p3;
    if (tid == 255) bsum[blockIdx.x] = ts[255];
}

__global__ void k_scan2(const int* __restrict__ bsum, int* __restrict__ boff) {
    __shared__ int s[256];
    int tid = threadIdx.x;
    s[tid] = (tid < SCAN_BLOCKS) ? bsum[tid] : 0;
    __syncthreads();
    for (int off = 1; off < 256; off <<= 1) {
        int v = (tid >= off) ? s[tid - off] : 0;
        __syncthreads();
        s[tid] += v;
        __syncthreads();
    }
    if (tid < SCAN_BLOCKS) boff[tid] = (tid > 0) ? s[tid - 1] : 0;
}

// scatter to bucket-major; boff applied inline; int2 loads; pack (src<<7)|(col&127)
__global__ void k_bscatter(const int* __restrict__ row, const int* __restrict__ col,
                           const int* __restrict__ bh, const int* __restrict__ boff,
                           int* __restrict__ ebuck) {
    __shared__ int cur[NB];
    int tid = threadIdx.x, blk = blockIdx.x;
    for (int i = tid; i < NB; i += 256) {
        int idx = i * NBLK + blk;
        cur[i] = (idx == 0) ? 0 : bh[idx - 1] + boff[(idx - 1) >> 10];
    }
    __syncthreads();
    int base = blk * EPB;
    const int2* c2p = (const int2*)&col[base];
    const int2* r2p = (const int2*)&row[base];
    for (int c = tid; c < EPB / 2; c += 256) {
        int2 cc = c2p[c];
        int2 rr = r2p[c];
        int p0 = atomicAdd(&cur[cc.x >> 7], 1);
        ebuck[p0] = (rr.x << 7) | (cc.x & 127);
        int p1 = atomicAdd(&cur[cc.y >> 7], 1);
        ebuck[p1] = (rr.y << 7) | (cc.y & 127);
    }
}

// per bucket (128 cols): counts (2-rep) + scan -> inc, dis
__global__ void __launch_bounds__(256) k_bcsr_a(const int* __restrict__ bh,
                                                const int* __restrict__ boff,
                                                const int* __restrict__ ebuck,
                                                int* __restrict__ inc, float* __restrict__ dis) {
    __shared__ int cnt[258];
    __shared__ int scn[128];
    int b = blockIdx.x, tid = threadIdx.x;
    int i0 = b * NBLK - 1, i1 = (b + 1) * NBLK - 1;
    int start = (b == 0) ? 0 : bh[i0] + boff[i0 >> 10];
    int end   = bh[i1] + boff[i1 >> 10];
    if (tid < 129) { cnt[tid] = 0; cnt[129 + tid] = 0; }
    __syncthreads();
    int c0 = (tid & 1) * 129;
    for (int j = start + tid; j < end; j += 256)
        atomicAdd(&cnt[c0 + (ebuck[j] & 127)], 1);
    __syncthreads();
    int v = 0;
    if (tid < 128) { v = cnt[tid] + cnt[129 + tid]; scn[tid] = v; }
    __syncthreads();
    for (int off = 1; off < 128; off <<= 1) {
        int t = (tid < 128 && tid >= off) ? scn[tid - off] : 0;
        __syncthreads();
        if (tid < 128) scn[tid] += t;
        __syncthreads();
    }
    if (tid < 128) {
        int colIdx = (b << 7) + tid;
        if (colIdx < NN) {
            inc[colIdx] = start + scn[tid];
            dis[colIdx] = (v > 0) ? rsqrtf((float)v) : 0.f;
        }
    }
}

// per bucket: scatter packed (src, w = dis[src]*dis[col]) into CSR order
__global__ void __launch_bounds__(256) k_bcsr_b(const int* __restrict__ bh,
                                                const int* __restrict__ boff,
                                                const int* __restrict__ ebuck,
                                                const int* __restrict__ inc,
                                                const float* __restrict__ dis,
                                                int2* __restrict__ esrc8) {
    __shared__ int cur[128];
    __shared__ float sdis[128];
    int b = blockIdx.x, tid = threadIdx.x;
    int i0 = b * NBLK - 1, i1 = (b + 1) * NBLK - 1;
    int start = (b == 0) ? 0 : bh[i0] + boff[i0 >> 10];
    int end   = bh[i1] + boff[i1 >> 10];
    if (tid < 128) {
        int colIdx = (b << 7) + tid;
        cur[tid]  = (colIdx == 0) ? 0 : ((colIdx <= NN) ? inc[colIdx - 1] : 0);
        sdis[tid] = (colIdx < NN) ? dis[colIdx] : 0.f;
    }
    __syncthreads();
    for (int j = start + tid; j < end; j += 256) {
        int e = ebuck[j];
        int c = e & 127, s = e >> 7;
        int pos = atomicAdd(&cur[c], 1);
        float w = dis[s] * sdis[c];
        esrc8[pos] = make_int2(s, __float_as_int(w));
    }
}

// layer1 gather + relu + K-mean + dense2. 8 lanes/node, 4-edge unrolled.
__global__ void k_gather1_mid(const int* __restrict__ inc, const int2* __restrict__ esrc8,
                              const float4* __restrict__ h1, const float4* __restrict__ r1,
                              const float4* __restrict__ Wi2, const float4* __restrict__ Wr2,
                              const float* __restrict__ b2,
                              float* __restrict__ h2, float* __restrict__ r2) {
    int tid = blockIdx.x * blockDim.x + threadIdx.x;
    int n = tid >> 3, l = tid & 7;
    if (n >= NN) return;
    int js = (n == 0) ? 0 : inc[n - 1];
    int je = inc[n];
    float4 acc = r1[(size_t)n * 8 + l];
    int j = js;
#define EDGE1(ss, ww) { \
        float4 v = h1[(size_t)(ss) * 8 + l]; \
        acc.x = fmaf(ww, v.x, acc.x); acc.y = fmaf(ww, v.y, acc.y); \
        acc.z = fmaf(ww, v.z, acc.z); acc.w = fmaf(ww, v.w, acc.w); }
    if ((j & 1) && j < je) {
        int2 e = esrc8[j];
        EDGE1(e.x, __int_as_float(e.y))
        j++;
    }
    for (; j + 3 < je; j += 4) {            // two int4 loads in flight
        int4 ep0 = *(const int4*)&esrc8[j];
        int4 ep1 = *(const int4*)&esrc8[j + 2];
        EDGE1(ep0.x, __int_as_float(ep0.y))
        EDGE1(ep0.z, __int_as_float(ep0.w))
        EDGE1(ep1.x, __int_as_float(ep1.y))
        EDGE1(ep1.z, __int_as_float(ep1.w))
    }
    for (; j + 1 < je; j += 2) {
        int4 ep = *(const int4*)&esrc8[j];
        EDGE1(ep.x, __int_as_float(ep.y))
        EDGE1(ep.z, __int_as_float(ep.w))
    }
    if (j < je) {
        int2 e = esrc8[j];
        EDGE1(e.x, __int_as_float(e.y))
    }
#undef EDGE1
    acc.x = fmaxf(acc.x, 0.f); acc.y = fmaxf(acc.y, 0.f);
    acc.z = fmaxf(acc.z, 0.f); acc.w = fmaxf(acc.w, 0.f);
    float4 h;
    h.x = 0.5f * (acc.x + __shfl_xor(acc.x, 4));
    h.y = 0.5f * (acc.y + __shfl_xor(acc.y, 4));
    h.z = 0.5f * (acc.z + __shfl_xor(acc.z, 4));
    h.w = 0.5f * (acc.w + __shfl_xor(acc.w, 4));
    float4 wi = Wi2[l], wr = Wr2[l];
    float p1 = h.x * wi.x + h.y * wi.y + h.z * wi.z + h.w * wi.w;
    float p2 = h.x * wr.x + h.y * wr.y + h.z * wr.z + h.w * wr.w;
    p1 += __shfl_xor(p1, 1); p1 += __shfl_xor(p1, 2);
    p2 += __shfl_xor(p2, 1); p2 += __shfl_xor(p2, 2);
    if ((l & 3) == 0) {
        int k = l >> 2;
        h2[n * 2 + k] = p1;
        r2[n * 2 + k] = p2 + b2[k];
    }
}

// layer2 gather: 4 lanes/node (halved reduce overhead), edge-parallel
__global__ void k_gather2(const int* __restrict__ inc, const int2* __restrict__ esrc8,
                          const float* __restrict__ h2, const float* __restrict__ r2,
                          float* __restrict__ out) {
    int tid = blockIdx.x * blockDim.x + threadIdx.x;
    int n = tid >> 2, l = tid & 3;
    if (n >= NN) return;
    int js = (n == 0) ? 0 : inc[n - 1];
    int je = inc[n];
    float a0 = 0.f, a1v = 0.f;
    for (int j = js + l; j < je; j += 4) {
        int2 e = esrc8[j];
        float w = __int_as_float(e.y);
        float2 hv = *(const float2*)&h2[(size_t)e.x * 2];
        a0  = fmaf(w, hv.x, a0);
        a1v = fmaf(w, hv.y, a1v);
    }
    a0  += __shfl_xor(a0, 1);  a0  += __shfl_xor(a0, 2);
    a1v += __shfl_xor(a1v, 1); a1v += __shfl_xor(a1v, 2);
    if (l == 0) {
        float2 rv = *(const float2*)&r2[(size_t)n * 2];
        out[n] = 0.5f * (fmaxf(a0 + rv.x, 0.f) + fmaxf(a1v + rv.y, 0.f));
    }
}

extern "C" void kernel_launch(void* const* d_in, const int* in_sizes, int n_in,
                              void* d_out, int out_size, void* d_ws, size_t ws_size,
                              hipStream_t stream) {
    const float* x   = (const float*)d_in[0];
    const int*   ei  = (const int*)d_in[1];
    const float* Wi1 = (const float*)d_in[2];
    const float* Wr1 = (const float*)d_in[3];
    const float* b1  = (const float*)d_in[4];
    const float* Wi2 = (const float*)d_in[5];
    const float* Wr2 = (const float*)d_in[6];
    const float* b2  = (const float*)d_in[7];
    float* out = (float*)d_out;

    const int* row = ei;
    const int* col = ei + NE;

    int*   bh    = (int*)d_ws;                       // 200192
    int*   bsum  = bh + SCANN;                       // 256
    int*   boff  = bsum + 256;                       // 256
    float* dis   = (float*)(boff + 256);             // NN
    int*   inc   = (int*)(dis + NN);                 // NN
    short* wpre  = (short*)(inc + NN);               // 8192 shorts
    int*   ebuck = (int*)(wpre + 8192);              // NE
    int2*  esrc8 = (int2*)(ebuck + NE);              // NE int2
    float* h1    = (float*)(esrc8 + NE);             // NN*32
    float* r1    = h1 + (size_t)NN * FH2;            // NN*32
    float* h2    = r1 + (size_t)NN * FH2;            // NN*2
    float* r2    = h2 + (size_t)NN * KS;             // NN*2

    const int B = 256;
    k_prep_w<<<1, B, 0, stream>>>(Wi1, Wr1, wpre);
    k_hist_dense1<<<NBLK + DENSE_BLOCKS, B, 0, stream>>>(col, bh, x, wpre, b1, h1, r1);
    k_scan1<<<SCAN_BLOCKS, B, 0, stream>>>(bh, bsum);
    k_scan2<<<1, 256, 0, stream>>>(bsum, boff);
    k_bscatter<<<NBLK, B, 0, stream>>>(row, col, bh, boff, ebuck);
    k_bcsr_a<<<NB, B, 0, stream>>>(bh, boff, ebuck, inc, dis);
    k_bcsr_b<<<NB, B, 0, stream>>>(bh, boff, ebuck, inc, dis, esrc8);
    k_gather1_mid<<<(NN * 8 + B - 1) / B, B, 0, stream>>>(inc, esrc8,
        (const float4*)h1, (const float4*)r1, (const float4*)Wi2, (const float4*)Wr2,
        b2, h2, r2);
    k_gather2<<<(NN * 4 + B - 1) / B, B, 0, stream>>>(inc, esrc8, h2, r2, out);
}